// Round 1
// baseline (72.209 us; speedup 1.0000x reference)
//
#include <hip/hip_runtime.h>

#define N_PED 2048
#define SEQ 8
#define NW 64   // 32-bit words per column bitmask (2048/32)

// ---------------------------------------------------------------------------
// Kernel 1: one wave (64 lanes) per row r.
//  - dist(r,c) = mean_t sqrt((xr-xc)^2 + (yr-yc)^2), matching JAX f32 numerics
//  - edge (r,c) iff dist<=1 and c<r  -> atomicOr bit r into column-major mask
//  - ck[r] = max active column (or -1), via wave shfl_xor max-reduce
// ---------------------------------------------------------------------------
__global__ __launch_bounds__(256) void edges_kernel(const float* __restrict__ va,
                                                    unsigned* __restrict__ colmask,
                                                    int* __restrict__ ck) {
    const int r    = (blockIdx.x * blockDim.x + threadIdx.x) >> 6;
    const int lane = threadIdx.x & 63;
    if (r >= N_PED) return;

    float xr[SEQ], yr[SEQ];
#pragma unroll
    for (int t = 0; t < SEQ; ++t) {
        xr[t] = va[t * N_PED + r];                 // coord 0
        yr[t] = va[SEQ * N_PED + t * N_PED + r];   // coord 1
    }

    int maxc = -1;
    for (int k = 0; k < N_PED / 64; ++k) {
        const int c = k * 64 + lane;
        float dsum = 0.0f;
#pragma unroll
        for (int t = 0; t < SEQ; ++t) {
            float dx = xr[t] - va[t * N_PED + c];
            float dy = yr[t] - va[SEQ * N_PED + t * N_PED + c];
            // no fma contraction: match jnp diff*diff summed then sqrt
            float s = __fadd_rn(__fmul_rn(dx, dx), __fmul_rn(dy, dy));
            float d = (s > 0.0f) ? __fsqrt_rn(s) : 0.0f;
            dsum = __fadd_rn(dsum, d);
        }
        const float dist = dsum * 0.125f;          // mean over SEQ=8 (exact pow2)
        if ((dist <= 1.0f) && (c < r)) {
            atomicOr(&colmask[c * NW + (r >> 5)], 1u << (r & 31));
            maxc = c;  // k ascending -> per-lane monotonic
        }
    }
#pragma unroll
    for (int off = 32; off >= 1; off >>= 1)
        maxc = max(maxc, __shfl_xor(maxc, off, 64));
    if (lane == 0) ck[r] = maxc;
}

// first set bit strictly below row r in a column bitmask, or -1
__device__ __forceinline__ int next_set_after(const unsigned* __restrict__ base, int r) {
    int start = r + 1;
    int w = start >> 5;
    if (w >= NW) return -1;
    unsigned bits = base[w] & (0xFFFFFFFFu << (start & 31));
    while (bits == 0u) {
        if (++w >= NW) return -1;
        bits = base[w];
    }
    return (w << 5) + (__ffs(bits) - 1);
}

// ---------------------------------------------------------------------------
// Kernel 2 (single block, 1024 threads):
//  succ[r] = next row consuming incarnation created at r (static!), pointer-
//  double to terminals, labels, rank remap, plus the v -> out copy.
// ---------------------------------------------------------------------------
__global__ __launch_bounds__(1024) void scan_kernel(const float* __restrict__ v,
                                                    const unsigned* __restrict__ colmask,
                                                    const int* __restrict__ ck,
                                                    float* __restrict__ out) {
    __shared__ int ckL[N_PED];
    __shared__ int succL[N_PED];
    __shared__ int labelL[N_PED];
    __shared__ int cumL[N_PED];
    __shared__ int waveS[16];
    const int t = threadIdx.x;

    // out[0:32768] = v (exact straight-through copy)
    {
        const float4* v4 = (const float4*)v;
        float4* o4 = (float4*)out;
        for (int j = t; j < (2 * SEQ * N_PED) / 4; j += 1024) o4[j] = v4[j];
    }

    for (int i = t; i < N_PED; i += 1024) ckL[i] = ck[i];
    __syncthreads();

    // successor of incarnation created at active row i: first edge in column
    // ck[i] below row i; terminal -> self. Inactive rows -> self (unused).
    for (int i = t; i < N_PED; i += 1024) {
        int s = i;
        const int c = ckL[i];
        if (c >= 0) {
            const int n = next_set_after(colmask + c * NW, i);
            if (n >= 0) s = n;
        }
        succL[i] = s;
    }
    __syncthreads();

    // pointer doubling: 2^11 >= 2048 covers max chain length
    for (int it = 0; it < 11; ++it) {
        const int a0 = succL[succL[t]];
        const int a1 = succL[succL[t + 1024]];
        __syncthreads();
        succL[t] = a0;
        succL[t + 1024] = a1;
        __syncthreads();
    }

    // node labels: first consumption of value i, then ck at the chain terminal
    for (int i = t; i < N_PED; i += 1024) {
        int fo;
        if (ckL[i] >= 0) fo = i;                              // row i active
        else fo = next_set_after(colmask + i * NW, i);        // first edge in col i
        labelL[i] = (fo < 0) ? i : ckL[succL[fo]];
        cumL[i] = 0;
    }
    __syncthreads();
    for (int i = t; i < N_PED; i += 1024) cumL[labelL[i]] = 1;  // present flags
    __syncthreads();

    // inclusive prefix sum over cumL[2048]: 2 elems/thread, wave scan + wave offsets
    const int lane = t & 63, wid = t >> 6;
    const int e0 = cumL[2 * t], e1 = cumL[2 * t + 1];
    const int ps = e0 + e1;
    int sc = ps;
#pragma unroll
    for (int off = 1; off < 64; off <<= 1) {
        const int n = __shfl_up(sc, off, 64);
        if (lane >= off) sc += n;
    }
    if (lane == 63) waveS[wid] = sc;
    __syncthreads();
    if (t == 0) {
        int acc = 0;
        for (int w = 0; w < 16; ++w) { const int x = waveS[w]; waveS[w] = acc; acc += x; }
    }
    __syncthreads();
    const int base = waveS[wid] + (sc - ps);  // exclusive prefix of this pair
    cumL[2 * t]     = base + e0;
    cumL[2 * t + 1] = base + e0 + e1;
    __syncthreads();

    // indices output (as float32, per flat-float32 readback of d_out)
    for (int i = t; i < N_PED; i += 1024)
        out[2 * SEQ * N_PED + i] = (float)(cumL[labelL[i]] - 1);
}

extern "C" void kernel_launch(void* const* d_in, const int* in_sizes, int n_in,
                              void* d_out, int out_size, void* d_ws, size_t ws_size,
                              hipStream_t stream) {
    const float* v  = (const float*)d_in[0];
    const float* va = (const float*)d_in[1];
    float* out = (float*)d_out;

    unsigned* colmask = (unsigned*)d_ws;                       // 2048*64*4 = 512 KB
    int* ck = (int*)((char*)d_ws + (size_t)N_PED * NW * 4);    // 8 KB

    hipMemsetAsync(colmask, 0, (size_t)N_PED * NW * 4, stream);
    edges_kernel<<<N_PED / 4, 256, 0, stream>>>(va, colmask, ck);
    scan_kernel<<<1, 1024, 0, stream>>>(v, colmask, ck, out);
}

// Round 2
// 41.025 us; speedup vs baseline: 1.7601x; 1.7601x over previous
//
#include <hip/hip_runtime.h>

#define N_PED 2048
#define SEQ 8
#define NW 64       // 32-bit words per column bitmask (2048/32)
#define CHUNK 1024  // columns staged in LDS per chunk (16 planes * 1024 * 4B = 64 KB)

// ---------------------------------------------------------------------------
// Kernel 1: 4 rows per block (one row per wave), LDS-staged column chunks.
//  - dist(r,c) = mean_t sqrt((xr-xc)^2 + (yr-yc)^2), matching JAX f32 numerics
//  - edge (r,c), c<r, dist<=1:
//      colmask bit (column-major), sum64 word-summary bit, minrow atomicMin
//  - ck[r] = max active column (or -1) via wave shfl_xor max-reduce
//  - blocks 0..31 also copy v -> out[0:32768] (straight-through output)
// ---------------------------------------------------------------------------
__global__ __launch_bounds__(256) void edges_kernel(const float* __restrict__ v,
                                                    const float* __restrict__ va,
                                                    unsigned* __restrict__ colmask,
                                                    unsigned long long* __restrict__ sum64,
                                                    unsigned* __restrict__ minrow,
                                                    int* __restrict__ ck,
                                                    float* __restrict__ out) {
    __shared__ float lds[16 * CHUNK];
    const int tid  = threadIdx.x;
    const int lane = tid & 63;
    const int wid  = tid >> 6;
    const int r    = blockIdx.x * 4 + wid;

    // v -> out copy, spread over the lowest-work blocks
    {
        const int g = blockIdx.x * 256 + tid;
        if (g < (2 * SEQ * N_PED) / 4)
            ((float4*)out)[g] = ((const float4*)v)[g];
    }

    float xr[SEQ], yr[SEQ];
#pragma unroll
    for (int t = 0; t < SEQ; ++t) {
        xr[t] = va[t * N_PED + r];                 // coord 0
        yr[t] = va[SEQ * N_PED + t * N_PED + r];   // coord 1
    }

    int maxc = -1;
    const int rmax = blockIdx.x * 4 + 3;
    for (int c0 = 0; c0 < rmax; c0 += CHUNK) {
        __syncthreads();  // previous chunk fully consumed
        // stage 16 planes x CHUNK cols as float4 (va plane stride = 2048 floats)
        for (int j = tid; j < 16 * CHUNK / 4; j += 256) {
            const int p  = j >> 8;          // plane 0..15
            const int c4 = j & 255;         // float4 index within plane chunk
            ((float4*)lds)[j] = ((const float4*)va)[p * (N_PED / 4) + (c0 >> 2) + c4];
        }
        __syncthreads();  // staging visible

        for (int kk = 0; kk < CHUNK / 64; ++kk) {
            if (c0 + kk * 64 >= r) break;   // wave-uniform triangle cutoff
            const int c = c0 + kk * 64 + lane;
            float dsum = 0.0f;
#pragma unroll
            for (int t = 0; t < SEQ; ++t) {
                const float dx = xr[t] - lds[t * CHUNK + kk * 64 + lane];
                const float dy = yr[t] - lds[(SEQ + t) * CHUNK + kk * 64 + lane];
                const float s = __fadd_rn(__fmul_rn(dx, dx), __fmul_rn(dy, dy));
                const float d = (s > 0.0f) ? __fsqrt_rn(s) : 0.0f;
                dsum = __fadd_rn(dsum, d);
            }
            const float dist = dsum * 0.125f;   // mean over SEQ=8 (exact pow2)
            if ((dist <= 1.0f) && (c < r)) {
                atomicOr(&colmask[c * NW + (r >> 5)], 1u << (r & 31));
                atomicOr(&sum64[c], 1ull << (r >> 5));
                atomicMin(&minrow[c], (unsigned)r);
                maxc = c;                       // ascending -> per-lane monotonic
            }
        }
    }
#pragma unroll
    for (int off = 32; off >= 1; off >>= 1)
        maxc = max(maxc, __shfl_xor(maxc, off, 64));
    if (lane == 0) ck[r] = maxc;
}

// ---------------------------------------------------------------------------
// Kernel 2 (single block, 1024 threads): static-successor construction via
// summary words (<=2 dependent global loads per active row), pointer doubling,
// labels via minrow, rank remap.
// ---------------------------------------------------------------------------
__global__ __launch_bounds__(1024) void scan_kernel(const unsigned* __restrict__ colmask,
                                                    const unsigned long long* __restrict__ sum64,
                                                    const unsigned* __restrict__ minrow,
                                                    const int* __restrict__ ck,
                                                    float* __restrict__ out) {
    __shared__ int ckL[N_PED];
    __shared__ int succL[N_PED];
    __shared__ int labelL[N_PED];
    __shared__ int cumL[N_PED];
    __shared__ unsigned long long sumL[N_PED];
    __shared__ int waveS[16];
    const int t = threadIdx.x;

    for (int i = t; i < N_PED; i += 1024) { ckL[i] = ck[i]; sumL[i] = sum64[i]; }
    __syncthreads();

    // successor of incarnation created at active row i: first bit > i in
    // column ck[i] (summary word -> at most 2 global word loads). terminal -> self.
    for (int i = t; i < N_PED; i += 1024) {
        int s = i;
        const int c = ckL[i];
        if (c >= 0 && i + 1 < N_PED) {
            const int start = i + 1;
            const int w0 = start >> 5;
            const unsigned long long sum = sumL[c];
            unsigned bits = 0u;
            if ((sum >> w0) & 1ull)
                bits = colmask[c * NW + w0] & (0xFFFFFFFFu << (start & 31));
            if (bits) s = (w0 << 5) + __ffs(bits) - 1;
            else {
                const unsigned long long rem = (w0 < 63) ? (sum & (~0ull << (w0 + 1))) : 0ull;
                if (rem) {
                    const int w2 = __ffsll(rem) - 1;
                    s = (w2 << 5) + __ffs(colmask[c * NW + w2]) - 1;
                }
            }
        }
        succL[i] = s;
    }
    __syncthreads();

    // pointer doubling: 2^11 >= 2048 covers max chain length
    for (int it = 0; it < 11; ++it) {
        const int a0 = succL[succL[t]];
        const int a1 = succL[succL[t + 1024]];
        __syncthreads();
        succL[t] = a0;
        succL[t + 1024] = a1;
        __syncthreads();
    }

    // labels: active row -> ck at its chain terminal; inactive -> via minrow
    for (int i = t; i < N_PED; i += 1024) {
        int fo;
        if (ckL[i] >= 0) fo = i;
        else {
            const unsigned mr = minrow[i];       // first edge row in column i (> i)
            fo = (mr == 0xFFFFFFFFu) ? -1 : (int)mr;
        }
        labelL[i] = (fo < 0) ? i : ckL[succL[fo]];
        cumL[i] = 0;
    }
    __syncthreads();
    for (int i = t; i < N_PED; i += 1024) cumL[labelL[i]] = 1;  // present flags
    __syncthreads();

    // inclusive prefix sum over cumL[2048]: 2 elems/thread, wave scan + offsets
    const int lane = t & 63, wid = t >> 6;
    const int e0 = cumL[2 * t], e1 = cumL[2 * t + 1];
    const int ps = e0 + e1;
    int sc = ps;
#pragma unroll
    for (int off = 1; off < 64; off <<= 1) {
        const int n = __shfl_up(sc, off, 64);
        if (lane >= off) sc += n;
    }
    if (lane == 63) waveS[wid] = sc;
    __syncthreads();
    if (t == 0) {
        int acc = 0;
        for (int w = 0; w < 16; ++w) { const int x = waveS[w]; waveS[w] = acc; acc += x; }
    }
    __syncthreads();
    const int base = waveS[wid] + (sc - ps);
    cumL[2 * t]     = base + e0;
    cumL[2 * t + 1] = base + e0 + e1;
    __syncthreads();

    for (int i = t; i < N_PED; i += 1024)
        out[2 * SEQ * N_PED + i] = (float)(cumL[labelL[i]] - 1);
}

extern "C" void kernel_launch(void* const* d_in, const int* in_sizes, int n_in,
                              void* d_out, int out_size, void* d_ws, size_t ws_size,
                              hipStream_t stream) {
    const float* v  = (const float*)d_in[0];
    const float* va = (const float*)d_in[1];
    float* out = (float*)d_out;
    char* ws = (char*)d_ws;

    unsigned* colmask           = (unsigned*)ws;                             // 512 KB
    unsigned long long* sum64   = (unsigned long long*)(ws + 512 * 1024);    // 16 KB
    unsigned* minrow            = (unsigned*)(ws + 528 * 1024);              // 8 KB
    int* ck                     = (int*)(ws + 536 * 1024);                   // 8 KB

    hipMemsetAsync(colmask, 0, 528 * 1024, stream);        // colmask + sum64
    hipMemsetAsync(minrow, 0xFF, 8 * 1024, stream);        // minrow = UINT_MAX
    edges_kernel<<<N_PED / 4, 256, 0, stream>>>(v, va, colmask, sum64, minrow, ck, out);
    scan_kernel<<<1, 1024, 0, stream>>>(colmask, sum64, minrow, ck, out);
}

// Round 3
// 32.419 us; speedup vs baseline: 2.2274x; 1.2655x over previous
//
#include <hip/hip_runtime.h>

#define N_PED 2048
#define SEQ 8
#define NW 64   // 32-bit words per column bitmask (2048/32)

// ws layout (all zero-initialized by init_kernel):
//   colmask   : 2048 cols * 64 u32   = 512 KB   (bit r set => edge (r,c), r>c)
//   sum64     : 2048 u64             =  16 KB   (bit w set => colmask word w nonzero)
//   minrow_enc: 2048 u32             =   8 KB   (max(2048-r) => min edge row; 0 => none)
//   ck        : 2048 i32             =   8 KB   (max edge col per row, -1 if none)
#define OFF_SUM64  (512 * 1024)
#define OFF_MINROW (528 * 1024)
#define OFF_CK     (536 * 1024)
#define WS_CLEAR_BYTES (536 * 1024)   // colmask + sum64 + minrow (ck is overwritten)

// ---------------------------------------------------------------------------
// Kernel 0: clear workspace + straight-through v -> out[0:32768] copy.
// 134 blocks x 256 threads: 34304 float4 = 536 KB clear, 8192 float4 copy.
// ---------------------------------------------------------------------------
__global__ __launch_bounds__(256) void init_kernel(const float* __restrict__ v,
                                                   float4* __restrict__ ws4,
                                                   float* __restrict__ out) {
    const int g = blockIdx.x * 256 + threadIdx.x;
    if (g < WS_CLEAR_BYTES / 16) ws4[g] = make_float4(0.f, 0.f, 0.f, 0.f);
    if (g < (2 * SEQ * N_PED) / 4) ((float4*)out)[g] = ((const float4*)v)[g];
}

// ---------------------------------------------------------------------------
// Kernel 1: 256 blocks x 512 threads (8 waves), one row per wave.
// Wave w<4: short row 4b+w (in [0,1024)); w>=4: long row 2047-4b-(w-4)
// (in [1024,2048)). SIMD s hosts waves {s, s+4}: per-SIMD columns =
// short + long = 2047 exactly -> perfect static balance on all 256 CUs.
// va fully staged in 128 KB LDS (1 block/CU).
// Per-pair arithmetic bit-identical to the verified version.
// ---------------------------------------------------------------------------
__global__ __launch_bounds__(512) void edges_kernel(const float* __restrict__ va,
                                                    unsigned* __restrict__ colmask,
                                                    unsigned long long* __restrict__ sum64,
                                                    unsigned* __restrict__ minrow_enc,
                                                    int* __restrict__ ck) {
    __shared__ float lds[16 * N_PED];   // 128 KB
    const int tid  = threadIdx.x;
    const int lane = tid & 63;
    const int w    = tid >> 6;
    const int b    = blockIdx.x;
    const int r    = (w < 4) ? (4 * b + w) : (2047 - 4 * b - (w - 4));

    // stage columns [0, SC) of all 16 planes (enough for every row in block)
    const int lmax = 2047 - 4 * b;                      // largest row in block
    const int SC   = (lmax + 63) & ~63;                 // staged cols (<=2048)
    const int CL4  = SC >> 2;
    for (int p = 0; p < 16; ++p) {
        const float4* src = (const float4*)va + p * (N_PED / 4);
        float4* dst = (float4*)(lds + p * N_PED);
        for (int j = tid; j < CL4; j += 512) dst[j] = src[j];
    }
    __syncthreads();

    float xr[SEQ], yr[SEQ];
#pragma unroll
    for (int t = 0; t < SEQ; ++t) {
        xr[t] = va[t * N_PED + r];                      // coord 0
        yr[t] = va[(SEQ + t) * N_PED + r];              // coord 1
    }

    int maxc = -1;
    const int ng = (r + 63) >> 6;                       // col groups covering [0, r)
    for (int k = 0; k < ng; ++k) {
        const int c = (k << 6) + lane;
        float dsum = 0.0f;
#pragma unroll
        for (int t = 0; t < SEQ; ++t) {
            const float dx = xr[t] - lds[t * N_PED + c];
            const float dy = yr[t] - lds[(SEQ + t) * N_PED + c];
            const float s = __fadd_rn(__fmul_rn(dx, dx), __fmul_rn(dy, dy));
            const float d = (s > 0.0f) ? __fsqrt_rn(s) : 0.0f;
            dsum = __fadd_rn(dsum, d);
        }
        const float dist = dsum * 0.125f;               // mean over SEQ=8 (exact)
        if ((dist <= 1.0f) && (c < r)) {
            atomicOr(&colmask[c * NW + (r >> 5)], 1u << (r & 31));
            atomicOr(&sum64[c], 1ull << (r >> 5));
            atomicMax(&minrow_enc[c], (unsigned)(N_PED - r));
            maxc = c;                                   // ascending -> monotonic
        }
    }
#pragma unroll
    for (int off = 32; off >= 1; off >>= 1)
        maxc = max(maxc, __shfl_xor(maxc, off, 64));
    if (lane == 0) ck[r] = maxc;
}

// ---------------------------------------------------------------------------
// Kernel 2 (single block, 1024 threads): static successors via summary words
// (<=2 global word loads per active row), pointer doubling, labels, rank remap.
// ---------------------------------------------------------------------------
__global__ __launch_bounds__(1024) void scan_kernel(const unsigned* __restrict__ colmask,
                                                    const unsigned long long* __restrict__ sum64,
                                                    const unsigned* __restrict__ minrow_enc,
                                                    const int* __restrict__ ck,
                                                    float* __restrict__ out) {
    __shared__ int ckL[N_PED];
    __shared__ int succL[N_PED];
    __shared__ int labelL[N_PED];
    __shared__ int cumL[N_PED];
    __shared__ unsigned long long sumL[N_PED];
    __shared__ int waveS[16];
    const int t = threadIdx.x;

    for (int i = t; i < N_PED; i += 1024) { ckL[i] = ck[i]; sumL[i] = sum64[i]; }
    __syncthreads();

    // successor of incarnation created at active row i: first bit > i in
    // column ck[i] (summary word -> at most 2 global word loads); terminal -> self
    for (int i = t; i < N_PED; i += 1024) {
        int s = i;
        const int c = ckL[i];
        if (c >= 0 && i + 1 < N_PED) {
            const int start = i + 1;
            const int w0 = start >> 5;
            const unsigned long long sum = sumL[c];
            unsigned bits = 0u;
            if ((sum >> w0) & 1ull)
                bits = colmask[c * NW + w0] & (0xFFFFFFFFu << (start & 31));
            if (bits) s = (w0 << 5) + __ffs(bits) - 1;
            else {
                const unsigned long long rem = (w0 < 63) ? (sum & (~0ull << (w0 + 1))) : 0ull;
                if (rem) {
                    const int w2 = __ffsll(rem) - 1;
                    s = (w2 << 5) + __ffs(colmask[c * NW + w2]) - 1;
                }
            }
        }
        succL[i] = s;
    }
    __syncthreads();

    // pointer doubling: 2^11 >= 2048 covers max chain length
    for (int it = 0; it < 11; ++it) {
        const int a0 = succL[succL[t]];
        const int a1 = succL[succL[t + 1024]];
        __syncthreads();
        succL[t] = a0;
        succL[t + 1024] = a1;
        __syncthreads();
    }

    // labels: active row -> ck at its chain terminal; inactive -> via minrow
    for (int i = t; i < N_PED; i += 1024) {
        int fo;
        if (ckL[i] >= 0) fo = i;
        else {
            const unsigned enc = minrow_enc[i];          // first edge row in col i
            fo = (enc == 0u) ? -1 : (int)(N_PED - enc);
        }
        labelL[i] = (fo < 0) ? i : ckL[succL[fo]];
        cumL[i] = 0;
    }
    __syncthreads();
    for (int i = t; i < N_PED; i += 1024) cumL[labelL[i]] = 1;  // present flags
    __syncthreads();

    // inclusive prefix sum over cumL[2048]: 2 elems/thread, wave scan + offsets
    const int lane = t & 63, wid = t >> 6;
    const int e0 = cumL[2 * t], e1 = cumL[2 * t + 1];
    const int ps = e0 + e1;
    int sc = ps;
#pragma unroll
    for (int off = 1; off < 64; off <<= 1) {
        const int n = __shfl_up(sc, off, 64);
        if (lane >= off) sc += n;
    }
    if (lane == 63) waveS[wid] = sc;
    __syncthreads();
    if (t == 0) {
        int acc = 0;
        for (int wv = 0; wv < 16; ++wv) { const int x = waveS[wv]; waveS[wv] = acc; acc += x; }
    }
    __syncthreads();
    const int base = waveS[wid] + (sc - ps);
    cumL[2 * t]     = base + e0;
    cumL[2 * t + 1] = base + e0 + e1;
    __syncthreads();

    for (int i = t; i < N_PED; i += 1024)
        out[2 * SEQ * N_PED + i] = (float)(cumL[labelL[i]] - 1);
}

extern "C" void kernel_launch(void* const* d_in, const int* in_sizes, int n_in,
                              void* d_out, int out_size, void* d_ws, size_t ws_size,
                              hipStream_t stream) {
    const float* v  = (const float*)d_in[0];
    const float* va = (const float*)d_in[1];
    float* out = (float*)d_out;
    char* ws = (char*)d_ws;

    unsigned* colmask         = (unsigned*)ws;
    unsigned long long* sum64 = (unsigned long long*)(ws + OFF_SUM64);
    unsigned* minrow_enc      = (unsigned*)(ws + OFF_MINROW);
    int* ck                   = (int*)(ws + OFF_CK);

    init_kernel<<<134, 256, 0, stream>>>(v, (float4*)ws, out);
    edges_kernel<<<256, 512, 0, stream>>>(va, colmask, sum64, minrow_enc, ck);
    scan_kernel<<<1, 1024, 0, stream>>>(colmask, sum64, minrow_enc, ck, out);
}